// Round 1
// baseline (51210.931 us; speedup 1.0000x reference)
//
#include <hip/hip_runtime.h>
#include <hip/hip_bf16.h>
#include <cstdint>
#include <cstddef>

#define S_LEN 512
#define B_SZ  512
#define T_LEN 160
#define E_DIM 256
#define H_DIM 512
#define V_DIM 34
#define G4    2048          // 4*H
#define KCAT  512           // per-part K (E+E or H)
#define EPS1  1e-12f

typedef unsigned short u16;

// ---------------- helpers ----------------
__device__ __forceinline__ float wave_reduce_sum(float v) {
#pragma unroll
  for (int m = 32; m >= 1; m >>= 1) v += __shfl_xor(v, m, 64);
  return v;
}
__device__ __forceinline__ float wave_reduce_max(float v) {
#pragma unroll
  for (int m = 32; m >= 1; m >>= 1) v = fmaxf(v, __shfl_xor(v, m, 64));
  return v;
}

__device__ __forceinline__ float4 load4(const float* p) { return *(const float4*)p; }
__device__ __forceinline__ float4 load4(const u16* p) {
  ushort4 u = *(const ushort4*)p;
  float4 r;
  r.x = __uint_as_float((uint32_t)u.x << 16);
  r.y = __uint_as_float((uint32_t)u.y << 16);
  r.z = __uint_as_float((uint32_t)u.z << 16);
  r.w = __uint_as_float((uint32_t)u.w << 16);
  return r;
}
__device__ __forceinline__ float load1(const float* p) { return *p; }
__device__ __forceinline__ float load1(const u16* p) {
  return __uint_as_float((uint32_t)(*p) << 16);
}
__device__ __forceinline__ u16 f2bf(float f) {
  uint32_t u = __float_as_uint(f);
  uint32_t r = (u + 0x7FFFu + ((u >> 16) & 1u)) >> 16;
  return (u16)r;
}

// ---------------- init ----------------
__global__ __launch_bounds__(256)
void init_state(const float* __restrict__ s0, const float* __restrict__ s1,
                const float* __restrict__ cs0, const float* __restrict__ cs1,
                float* __restrict__ h0, float* __restrict__ h1,
                float* __restrict__ c0, float* __restrict__ c1) {
  int idx = blockIdx.x * blockDim.x + threadIdx.x;  // < B*H
  int j = idx & (H_DIM - 1);
  h0[idx] = s0[j];
  h1[idx] = s1[j];
  c0[idx] = cs0[j];
  c1[idx] = cs1[j];
}

// ---------------- fp32 -> bf16 conversion (K/V) ----------------
__global__ __launch_bounds__(256)
void conv_bf16(const float* __restrict__ in, u16* __restrict__ outp, int n4) {
  int i = blockIdx.x * blockDim.x + threadIdx.x;
  int stride = gridDim.x * blockDim.x;
  for (; i < n4; i += stride) {
    float4 f = ((const float4*)in)[i];
    ushort4 u;
    u.x = f2bf(f.x); u.y = f2bf(f.y); u.z = f2bf(f.z); u.w = f2bf(f.w);
    ((ushort4*)outp)[i] = u;
  }
}

// ---------------- fused attention (+scoring, +pack x0) ----------------
// block b (512 blocks x 256 threads): q = h1 @ Wq^T + bq ; scores over S;
// masked softmax + renorm ; ctx ; out[b, t-1, :] (t>=1) ; x0 = [emb_t, ctx] (t<T)
template <typename KVT>
__global__ __launch_bounds__(256)
void attend_kernel(const KVT* __restrict__ key, const KVT* __restrict__ value,
                   const float* __restrict__ mask, const int* __restrict__ labels,
                   const float* __restrict__ Wq, const float* __restrict__ bq,
                   const float* __restrict__ Wsc, const float* __restrict__ bsc,
                   const float* __restrict__ Emb, const float* __restrict__ h1,
                   float* __restrict__ x0, float* __restrict__ out, int t) {
  __shared__ float h1s[H_DIM];
  __shared__ float qs[E_DIM];
  __shared__ float sc[S_LEN];
  __shared__ float ctxs[E_DIM];
  __shared__ float red[8];

  const int b = blockIdx.x;
  const int tid = threadIdx.x;
  const int lane = tid & 63;
  const int wave = tid >> 6;

  // stage h1 row
#pragma unroll
  for (int j = tid; j < H_DIM; j += 256) h1s[j] = h1[b * H_DIM + j];
  __syncthreads();

  // q[e] = bq[e] + sum_h h1[h] * Wq[e, h]   (wave-cooperative, coalesced Wq rows)
  {
    const float* hp = &h1s[lane * 8];
    float h0v = hp[0], h1v = hp[1], h2v = hp[2], h3v = hp[3];
    float h4v = hp[4], h5v = hp[5], h6v = hp[6], h7v = hp[7];
    for (int eo = 0; eo < 64; ++eo) {
      int e = (wave << 6) | eo;
      const float4* wrow = reinterpret_cast<const float4*>(Wq + (size_t)e * H_DIM);
      float4 wa = wrow[lane * 2];
      float4 wb = wrow[lane * 2 + 1];
      float acc = wa.x * h0v + wa.y * h1v + wa.z * h2v + wa.w * h3v +
                  wb.x * h4v + wb.y * h5v + wb.z * h6v + wb.w * h7v;
      acc = wave_reduce_sum(acc);
      if (lane == 0) qs[e] = acc + bq[e];
    }
  }
  __syncthreads();

  // scores[s] = key[s,b,:] . q      (wave per row, lane covers 4 e's)
  {
    float q0 = qs[lane * 4 + 0];
    float q1 = qs[lane * 4 + 1];
    float q2 = qs[lane * 4 + 2];
    float q3 = qs[lane * 4 + 3];
    const KVT* kbase = key + (size_t)b * E_DIM + lane * 4;
    for (int s = wave; s < S_LEN; s += 4) {
      float4 k4 = load4(kbase + (size_t)s * (B_SZ * E_DIM));
      float acc = k4.x * q0 + k4.y * q1 + k4.z * q2 + k4.w * q3;
      acc = wave_reduce_sum(acc);
      if (lane == 0) sc[s] = acc;
    }
  }
  __syncthreads();

  // masked softmax + renormalize: alpha = p*mask / max(sum(p*mask), EPS*sum(p))
  float v0 = sc[tid], v1 = sc[tid + 256];
  {
    float lm = wave_reduce_max(fmaxf(v0, v1));
    if (lane == 0) red[wave] = lm;
  }
  __syncthreads();
  float smax = fmaxf(fmaxf(red[0], red[1]), fmaxf(red[2], red[3]));
  __syncthreads();  // everyone has read red[] before reuse
  float m0 = mask[(size_t)b * S_LEN + tid];
  float m1 = mask[(size_t)b * S_LEN + tid + 256];
  float p0 = __expf(v0 - smax), p1 = __expf(v1 - smax);
  float pm0 = p0 * m0, pm1 = p1 * m1;
  {
    float sP = wave_reduce_sum(p0 + p1);
    float sPM = wave_reduce_sum(pm0 + pm1);
    if (lane == 0) { red[wave] = sP; red[4 + wave] = sPM; }
  }
  __syncthreads();
  float P  = red[0] + red[1] + red[2] + red[3];
  float PM = red[4] + red[5] + red[6] + red[7];
  float inv = 1.f / fmaxf(PM, EPS1 * P);
  sc[tid] = pm0 * inv;
  sc[tid + 256] = pm1 * inv;
  __syncthreads();

  // ctx[e] = sum_s alpha[s] * value[s,b,e]   (thread e, coalesced)
  {
    float acc = 0.f;
    const KVT* vp = value + (size_t)b * E_DIM + tid;
#pragma unroll 8
    for (int s = 0; s < S_LEN; ++s) {
      acc += sc[s] * load1(vp);
      vp += (size_t)B_SZ * E_DIM;
    }
    ctxs[tid] = acc;
    if (t < T_LEN) {
      int lab = labels[(size_t)b * T_LEN + t];
      x0[(size_t)b * KCAT + tid] = Emb[(size_t)lab * E_DIM + tid];
      x0[(size_t)b * KCAT + E_DIM + tid] = acc;
    }
  }
  __syncthreads();

  // scoring: out[b, t-1, v] = [h1, ctx] . Wsc[v,:] + bsc[v]
  if (t >= 1) {
    for (int v = wave; v < V_DIM; v += 4) {
      const float4* wr = reinterpret_cast<const float4*>(Wsc + (size_t)v * (H_DIM + E_DIM));
      float4 w0 = wr[lane];
      float4 w1 = wr[lane + 64];
      float4 w2 = wr[lane + 128];
      const float* ha = &h1s[4 * lane];
      const float* hb = &h1s[256 + 4 * lane];
      const float* cx = &ctxs[4 * lane];
      float acc = w0.x * ha[0] + w0.y * ha[1] + w0.z * ha[2] + w0.w * ha[3] +
                  w1.x * hb[0] + w1.y * hb[1] + w1.z * hb[2] + w1.w * hb[3] +
                  w2.x * cx[0] + w2.y * cx[1] + w2.z * cx[2] + w2.w * cx[3];
      acc = wave_reduce_sum(acc);
      if (lane == 0) out[((size_t)b * T_LEN + (t - 1)) * V_DIM + v] = acc + bsc[v];
    }
  }
}

// ---------------- LSTM gate GEMM ----------------
// g[m, n] = bi[n] + bh[n] + sum_k A1[m,k]*W1[n,k] + sum_k A2[m,k]*W2[n,k]
// A1, A2: (512, 512) row-major ; W1, W2: (2048, 512) row-major ; g: (512, 2048)
#define BM 64
#define BN 64
#define BKK 16

__global__ __launch_bounds__(256)
void gemm_gates(const float* __restrict__ A1, const float* __restrict__ A2,
                const float* __restrict__ W1, const float* __restrict__ W2,
                const float* __restrict__ bi, const float* __restrict__ bh,
                float* __restrict__ g) {
  __shared__ float As[BKK][BM + 4];
  __shared__ float Bs[BKK][BN + 4];

  const int tid = threadIdx.x;
  const int m0 = blockIdx.y * BM;
  const int n0 = blockIdx.x * BN;
  const int tx = tid & 15;   // output col group
  const int ty = tid >> 4;   // output row group
  const int lk = tid & 15;   // loader: k
  const int lr = tid >> 4;   // loader: row base

  float acc[4][4];
#pragma unroll
  for (int i = 0; i < 4; ++i)
#pragma unroll
    for (int j = 0; j < 4; ++j) acc[i][j] = 0.f;

  for (int kt = 0; kt < 64; ++kt) {
    const float* Ap; const float* Wp; int k0;
    if (kt < 32) { Ap = A1; Wp = W1; k0 = kt * BKK; }
    else         { Ap = A2; Wp = W2; k0 = kt * BKK - 512; }

    __syncthreads();
#pragma unroll
    for (int i = 0; i < 4; ++i) {
      As[lk][lr + 16 * i] = Ap[(size_t)(m0 + lr + 16 * i) * KCAT + k0 + lk];
      Bs[lk][lr + 16 * i] = Wp[(size_t)(n0 + lr + 16 * i) * KCAT + k0 + lk];
    }
    __syncthreads();

#pragma unroll
    for (int kk = 0; kk < BKK; ++kk) {
      float4 a = *(const float4*)&As[kk][ty * 4];
      float4 w = *(const float4*)&Bs[kk][tx * 4];
      acc[0][0] += a.x * w.x; acc[0][1] += a.x * w.y; acc[0][2] += a.x * w.z; acc[0][3] += a.x * w.w;
      acc[1][0] += a.y * w.x; acc[1][1] += a.y * w.y; acc[1][2] += a.y * w.z; acc[1][3] += a.y * w.w;
      acc[2][0] += a.z * w.x; acc[2][1] += a.z * w.y; acc[2][2] += a.z * w.z; acc[2][3] += a.z * w.w;
      acc[3][0] += a.w * w.x; acc[3][1] += a.w * w.y; acc[3][2] += a.w * w.z; acc[3][3] += a.w * w.w;
    }
  }

#pragma unroll
  for (int i = 0; i < 4; ++i) {
    int m = m0 + ty * 4 + i;
#pragma unroll
    for (int j = 0; j < 4; ++j) {
      int n = n0 + tx * 4 + j;
      g[(size_t)m * G4 + n] = acc[i][j] + bi[n] + bh[n];
    }
  }
}

// ---------------- LSTM pointwise gates ----------------
__global__ __launch_bounds__(256)
void lstm_point(const float* __restrict__ g, float* __restrict__ h, float* __restrict__ c) {
  int idx = blockIdx.x * blockDim.x + threadIdx.x;  // < B*H
  int b = idx >> 9;
  int j = idx & 511;
  const float* gr = g + (size_t)b * G4;
  float gi = gr[j];
  float gf = gr[H_DIM + j];
  float gg = gr[2 * H_DIM + j];
  float go = gr[3 * H_DIM + j];
  float si = 1.f / (1.f + __expf(-gi));
  float sf = 1.f / (1.f + __expf(-gf));
  float so = 1.f / (1.f + __expf(-go));
  float tg = tanhf(gg);
  float cn = sf * c[idx] + si * tg;
  float hn = so * tanhf(cn);
  c[idx] = cn;
  h[idx] = hn;
}

// ---------------- host ----------------
extern "C" void kernel_launch(void* const* d_in, const int* in_sizes, int n_in,
                              void* d_out, int out_size, void* d_ws, size_t ws_size,
                              hipStream_t stream) {
  (void)in_sizes; (void)n_in; (void)out_size;

  const float* key    = (const float*)d_in[0];
  const float* value  = (const float*)d_in[1];
  const float* mask   = (const float*)d_in[2];
  const int*   labels = (const int*)d_in[3];
  const float* Wq     = (const float*)d_in[4];
  const float* bq     = (const float*)d_in[5];
  const float* Wsc    = (const float*)d_in[6];
  const float* bsc    = (const float*)d_in[7];
  const float* Emb    = (const float*)d_in[8];
  const float* Wih0   = (const float*)d_in[9];
  const float* Whh0   = (const float*)d_in[10];
  const float* bih0   = (const float*)d_in[11];
  const float* bhh0   = (const float*)d_in[12];
  const float* Wih1   = (const float*)d_in[13];
  const float* Whh1   = (const float*)d_in[14];
  const float* bih1   = (const float*)d_in[15];
  const float* bhh1   = (const float*)d_in[16];
  const float* s0     = (const float*)d_in[17];
  const float* s1     = (const float*)d_in[18];
  const float* cs0    = (const float*)d_in[19];
  const float* cs1    = (const float*)d_in[20];
  float* out = (float*)d_out;

  char* ws = (char*)d_ws;
  size_t off = 0;
  auto alloc = [&](size_t bytes) -> void* {
    void* p = ws + off;
    off += (bytes + 255) & ~(size_t)255;
    return p;
  };
  float* h0 = (float*)alloc((size_t)B_SZ * H_DIM * 4);
  float* c0 = (float*)alloc((size_t)B_SZ * H_DIM * 4);
  float* h1 = (float*)alloc((size_t)B_SZ * H_DIM * 4);
  float* c1 = (float*)alloc((size_t)B_SZ * H_DIM * 4);
  float* x0 = (float*)alloc((size_t)B_SZ * KCAT * 4);
  float* g  = (float*)alloc((size_t)B_SZ * G4 * 4);

  const size_t kv_elems = (size_t)S_LEN * B_SZ * E_DIM;
  const size_t kv_bytes = kv_elems * 2;  // bf16
  bool bf16kv = (ws_size >= off + 2 * kv_bytes + 512);
  u16* kb = nullptr; u16* vb = nullptr;
  if (bf16kv) {
    kb = (u16*)alloc(kv_bytes);
    vb = (u16*)alloc(kv_bytes);
  }

  init_state<<<(B_SZ * H_DIM) / 256, 256, 0, stream>>>(s0, s1, cs0, cs1, h0, h1, c0, c1);

  if (bf16kv) {
    int n4 = (int)(kv_elems / 4);
    conv_bf16<<<4096, 256, 0, stream>>>(key, kb, n4);
    conv_bf16<<<4096, 256, 0, stream>>>(value, vb, n4);
  }

  dim3 gemm_grid(G4 / BN, B_SZ / BM);
  for (int t = 0; t <= T_LEN; ++t) {
    if (bf16kv) {
      attend_kernel<u16><<<B_SZ, 256, 0, stream>>>(
          kb, vb, mask, labels, Wq, bq, Wsc, bsc, Emb, h1, x0, out, t);
    } else {
      attend_kernel<float><<<B_SZ, 256, 0, stream>>>(
          key, value, mask, labels, Wq, bq, Wsc, bsc, Emb, h1, x0, out, t);
    }
    if (t < T_LEN) {
      gemm_gates<<<gemm_grid, 256, 0, stream>>>(x0, h0, Wih0, Whh0, bih0, bhh0, g);
      lstm_point<<<(B_SZ * H_DIM) / 256, 256, 0, stream>>>(g, h0, c0);
      gemm_gates<<<gemm_grid, 256, 0, stream>>>(h0, h1, Wih1, Whh1, bih1, bhh1, g);
      lstm_point<<<(B_SZ * H_DIM) / 256, 256, 0, stream>>>(g, h1, c1);
    }
  }
}

// Round 2
// 36568.875 us; speedup vs baseline: 1.4004x; 1.4004x over previous
//
#include <hip/hip_runtime.h>
#include <hip/hip_bf16.h>
#include <cstdint>
#include <cstddef>

#define S_LEN 512
#define B_SZ  512
#define T_LEN 160
#define E_DIM 256
#define H_DIM 512
#define V_DIM 34
#define G4    2048          // 4*H
#define KCAT  512
#define EPS1  1e-12f

typedef unsigned short u16;
typedef __attribute__((ext_vector_type(8))) short bf16x8;
typedef __attribute__((ext_vector_type(4))) float f32x4;

#define SMEM_BYTES 18432    // max(2*64*72*2 staging, 64*68*4 C-tile)

// ---------------- helpers ----------------
__device__ __forceinline__ float wave_reduce_sum(float v) {
#pragma unroll
  for (int m = 32; m >= 1; m >>= 1) v += __shfl_xor(v, m, 64);
  return v;
}
__device__ __forceinline__ float wave_reduce_max(float v) {
#pragma unroll
  for (int m = 32; m >= 1; m >>= 1) v = fmaxf(v, __shfl_xor(v, m, 64));
  return v;
}
__device__ __forceinline__ float4 load4(const float* p) { return *(const float4*)p; }
__device__ __forceinline__ float4 load4(const u16* p) {
  ushort4 u = *(const ushort4*)p;
  float4 r;
  r.x = __uint_as_float((uint32_t)u.x << 16);
  r.y = __uint_as_float((uint32_t)u.y << 16);
  r.z = __uint_as_float((uint32_t)u.z << 16);
  r.w = __uint_as_float((uint32_t)u.w << 16);
  return r;
}
__device__ __forceinline__ float load1(const float* p) { return *p; }
__device__ __forceinline__ float load1(const u16* p) {
  return __uint_as_float((uint32_t)(*p) << 16);
}
__device__ __forceinline__ u16 f2bf(float f) {
  uint32_t u = __float_as_uint(f);
  uint32_t r = (u + 0x7FFFu + ((u >> 16) & 1u)) >> 16;
  return (u16)r;
}
__device__ __forceinline__ float sigm(float x) { return 1.f / (1.f + __expf(-x)); }

// ---------------- shared MFMA K=512 tile: C[64x64] = A(64x512) . W(64x512)^T ----
// A row m at A + m*lda (bf16, k contiguous). W row n' at W + n'*512.
// acc[fm][fn]: wave (2x2 of 32x32), frags 16x16.
__device__ __forceinline__ void mfma_k512(const u16* A, int lda, const u16* W,
                                          int m0, int n0, char* smem,
                                          f32x4 (&acc)[2][2]) {
  u16 (*As)[72] = (u16(*)[72])smem;
  u16 (*Ws)[72] = (u16(*)[72])(smem + 64 * 72 * 2);
  const int tid = threadIdx.x;
  const int lane = tid & 63, wave = tid >> 6;
  const int wm = (wave >> 1) * 32, wn = (wave & 1) * 32;
  const int row = lane & 15, kq = (lane >> 4) * 8;

  for (int k0 = 0; k0 < 512; k0 += 64) {
    __syncthreads();
#pragma unroll
    for (int i = tid; i < 512; i += 256) {
      int r = i >> 3, c = (i & 7) * 8;
      *(bf16x8*)&As[r][c] = *(const bf16x8*)(A + (size_t)(m0 + r) * lda + k0 + c);
      *(bf16x8*)&Ws[r][c] = *(const bf16x8*)(W + (size_t)(n0 + r) * 512 + k0 + c);
    }
    __syncthreads();
#pragma unroll
    for (int kk = 0; kk < 64; kk += 32) {
      bf16x8 a0 = *(const bf16x8*)&As[wm + row][kk + kq];
      bf16x8 a1 = *(const bf16x8*)&As[wm + 16 + row][kk + kq];
      bf16x8 b0 = *(const bf16x8*)&Ws[wn + row][kk + kq];
      bf16x8 b1 = *(const bf16x8*)&Ws[wn + 16 + row][kk + kq];
      acc[0][0] = __builtin_amdgcn_mfma_f32_16x16x32_bf16(a0, b0, acc[0][0], 0, 0, 0);
      acc[0][1] = __builtin_amdgcn_mfma_f32_16x16x32_bf16(a0, b1, acc[0][1], 0, 0, 0);
      acc[1][0] = __builtin_amdgcn_mfma_f32_16x16x32_bf16(a1, b0, acc[1][0], 0, 0, 0);
      acc[1][1] = __builtin_amdgcn_mfma_f32_16x16x32_bf16(a1, b1, acc[1][1], 0, 0, 0);
    }
  }
}

// ---------------- init ----------------
__global__ __launch_bounds__(256)
void init_state(const float* __restrict__ s0, const float* __restrict__ s1,
                const float* __restrict__ cs0, const float* __restrict__ cs1,
                u16* __restrict__ xcat0, u16* __restrict__ xcat1,
                float* __restrict__ h1f,
                float* __restrict__ c0, float* __restrict__ c1) {
  int idx = blockIdx.x * blockDim.x + threadIdx.x;  // < B*H
  int b = idx >> 9, j = idx & 511;
  xcat0[(size_t)b * 1024 + 512 + j] = f2bf(s0[j]);
  xcat1[(size_t)b * 1024 + 512 + j] = f2bf(s1[j]);
  h1f[idx] = s1[j];
  c0[idx] = cs0[j];
  c1[idx] = cs1[j];
}

// ---------------- fp32 -> bf16 (K/V) ----------------
__global__ __launch_bounds__(256)
void conv_bf16(const float* __restrict__ in, u16* __restrict__ outp, int n4) {
  int i = blockIdx.x * blockDim.x + threadIdx.x;
  int stride = gridDim.x * blockDim.x;
  for (; i < n4; i += stride) {
    float4 f = ((const float4*)in)[i];
    ushort4 u;
    u.x = f2bf(f.x); u.y = f2bf(f.y); u.z = f2bf(f.z); u.w = f2bf(f.w);
    ((ushort4*)outp)[i] = u;
  }
}

// ---------------- weight pack: Wp[(j*4+g)][k] = W[g*512+j][k], bf16 ----------------
__global__ __launch_bounds__(256)
void pack_w(const float* __restrict__ in, u16* __restrict__ outp) {
  int idx = blockIdx.x * 256 + threadIdx.x;   // 2048*64 = 131072 threads
  int k = (idx & 63) * 8;
  int np = idx >> 6;                          // n' = j*4+g
  int j = np >> 2, g = np & 3;
  const float* src = in + ((size_t)(g * 512 + j)) * 512 + k;
  float4 f0 = *(const float4*)src;
  float4 f1 = *(const float4*)(src + 4);
  ushort4 o0, o1;
  o0.x = f2bf(f0.x); o0.y = f2bf(f0.y); o0.z = f2bf(f0.z); o0.w = f2bf(f0.w);
  o1.x = f2bf(f1.x); o1.y = f2bf(f1.y); o1.z = f2bf(f1.z); o1.w = f2bf(f1.w);
  *(ushort4*)(outp + (size_t)np * 512 + k) = o0;
  *(ushort4*)(outp + (size_t)np * 512 + k + 4) = o1;
}

__global__ __launch_bounds__(256)
void pack_bias(const float* bih0, const float* bhh0,
               const float* bih1, const float* bhh1,
               float* bias0p, float* bias1p) {
  int np = blockIdx.x * 256 + threadIdx.x;  // < 2048
  int j = np >> 2, g = np & 3;
  int n = g * 512 + j;
  bias0p[np] = bih0[n] + bhh0[n];
  bias1p[np] = bih1[n] + bhh1[n];
}

// ---------------- kernel A: attend (blocks 0..511) + recurrent partial GEMMs ----
// pg0 = h0b @ Whh0p^T , pg1 = h1b @ Whh1p^T   (blocks 512..1023)
template <typename KVT>
__global__ __launch_bounds__(256)
void fusedA(const KVT* key, const KVT* value,
            const float* mask, const int* labels,
            const float* Wq, const float* bq,
            const float* Wsc, const float* bsc,
            const float* Emb, const float* h1f,
            u16* xcat0, const u16* xcat1,
            const u16* Whh0p, const u16* Whh1p,
            float* pg0, float* pg1,
            float* out, int t) {
  __shared__ char smem[SMEM_BYTES];
  const int tid = threadIdx.x;
  const int lane = tid & 63;
  const int wave = tid >> 6;

  if (blockIdx.x >= 512) {
    // -------- recurrent partial GEMM --------
    if (t >= T_LEN) return;
    int gb = blockIdx.x - 512;
    const u16* Asrc; const u16* Wsrc; float* pg;
    if (gb < 256) { Asrc = xcat0 + 512; Wsrc = Whh0p; pg = pg0; }
    else          { gb -= 256; Asrc = xcat1 + 512; Wsrc = Whh1p; pg = pg1; }
    int m0 = (gb >> 5) * 64, n0 = (gb & 31) * 64;
    f32x4 acc[2][2] = {};
    mfma_k512(Asrc, 1024, Wsrc, m0, n0, smem, acc);
    const int wm = (wave >> 1) * 32, wn = (wave & 1) * 32;
    const int col = lane & 15, r4 = (lane >> 4) * 4;
#pragma unroll
    for (int fm = 0; fm < 2; ++fm)
#pragma unroll
      for (int fn = 0; fn < 2; ++fn) {
        int cc = n0 + wn + fn * 16 + col;
#pragma unroll
        for (int r = 0; r < 4; ++r) {
          int rr = m0 + wm + fm * 16 + r4 + r;
          pg[(size_t)rr * G4 + cc] = acc[fm][fn][r];
        }
      }
    return;
  }

  // -------- attend --------
  float* h1s  = (float*)smem;          // 512
  float* qs   = h1s + 512;             // 256
  float* scb  = qs + 256;              // 512
  float* ctxs = scb + 512;             // 256
  float* red  = ctxs + 256;            // 8
  const int b = blockIdx.x;

#pragma unroll
  for (int j = tid; j < H_DIM; j += 256) h1s[j] = h1f[(size_t)b * H_DIM + j];
  __syncthreads();

  // q = h1 @ Wq^T + bq
  {
    const float* hp = &h1s[lane * 8];
    float h0v = hp[0], h1v = hp[1], h2v = hp[2], h3v = hp[3];
    float h4v = hp[4], h5v = hp[5], h6v = hp[6], h7v = hp[7];
    for (int eo = 0; eo < 64; ++eo) {
      int e = (wave << 6) | eo;
      const float4* wrow = reinterpret_cast<const float4*>(Wq + (size_t)e * H_DIM);
      float4 wa = wrow[lane * 2];
      float4 wb = wrow[lane * 2 + 1];
      float acc = wa.x * h0v + wa.y * h1v + wa.z * h2v + wa.w * h3v +
                  wb.x * h4v + wb.y * h5v + wb.z * h6v + wb.w * h7v;
      acc = wave_reduce_sum(acc);
      if (lane == 0) qs[e] = acc + bq[e];
    }
  }
  __syncthreads();

  // scores
  {
    float q0 = qs[lane * 4 + 0];
    float q1 = qs[lane * 4 + 1];
    float q2 = qs[lane * 4 + 2];
    float q3 = qs[lane * 4 + 3];
    const KVT* kbase = key + (size_t)b * E_DIM + lane * 4;
    for (int s = wave; s < S_LEN; s += 4) {
      float4 k4 = load4(kbase + (size_t)s * (B_SZ * E_DIM));
      float acc = k4.x * q0 + k4.y * q1 + k4.z * q2 + k4.w * q3;
      acc = wave_reduce_sum(acc);
      if (lane == 0) scb[s] = acc;
    }
  }
  __syncthreads();

  // masked softmax + renorm
  float v0 = scb[tid], v1 = scb[tid + 256];
  {
    float lm = wave_reduce_max(fmaxf(v0, v1));
    if (lane == 0) red[wave] = lm;
  }
  __syncthreads();
  float smax = fmaxf(fmaxf(red[0], red[1]), fmaxf(red[2], red[3]));
  __syncthreads();
  float m0 = mask[(size_t)b * S_LEN + tid];
  float m1 = mask[(size_t)b * S_LEN + tid + 256];
  float p0 = __expf(v0 - smax), p1 = __expf(v1 - smax);
  float pm0 = p0 * m0, pm1 = p1 * m1;
  {
    float sP = wave_reduce_sum(p0 + p1);
    float sPM = wave_reduce_sum(pm0 + pm1);
    if (lane == 0) { red[wave] = sP; red[4 + wave] = sPM; }
  }
  __syncthreads();
  float P  = red[0] + red[1] + red[2] + red[3];
  float PM = red[4] + red[5] + red[6] + red[7];
  float inv = 1.f / fmaxf(PM, EPS1 * P);
  scb[tid] = pm0 * inv;
  scb[tid + 256] = pm1 * inv;
  __syncthreads();

  // ctx + pack x_t (bf16)
  {
    float acc = 0.f;
    const KVT* vp = value + (size_t)b * E_DIM + tid;
#pragma unroll 8
    for (int s = 0; s < S_LEN; ++s) {
      acc += scb[s] * load1(vp);
      vp += (size_t)B_SZ * E_DIM;
    }
    ctxs[tid] = acc;
    if (t < T_LEN) {
      int lab = labels[(size_t)b * T_LEN + t];
      xcat0[(size_t)b * 1024 + tid] = f2bf(Emb[(size_t)lab * E_DIM + tid]);
      xcat0[(size_t)b * 1024 + E_DIM + tid] = f2bf(acc);
    }
  }
  __syncthreads();

  // scoring (fp32 h1, fp32 ctx)
  if (t >= 1) {
    for (int v = wave; v < V_DIM; v += 4) {
      const float4* wr = reinterpret_cast<const float4*>(Wsc + (size_t)v * (H_DIM + E_DIM));
      float4 w0 = wr[lane];
      float4 w1 = wr[lane + 64];
      float4 w2 = wr[lane + 128];
      const float* ha = &h1s[4 * lane];
      const float* hb = &h1s[256 + 4 * lane];
      const float* cx = &ctxs[4 * lane];
      float acc = w0.x * ha[0] + w0.y * ha[1] + w0.z * ha[2] + w0.w * ha[3] +
                  w1.x * hb[0] + w1.y * hb[1] + w1.z * hb[2] + w1.w * hb[3] +
                  w2.x * cx[0] + w2.y * cx[1] + w2.z * cx[2] + w2.w * cx[3];
      acc = wave_reduce_sum(acc);
      if (lane == 0) out[((size_t)b * T_LEN + (t - 1)) * V_DIM + v] = acc + bsc[v];
    }
  }
}

// ---------------- cell kernel: x-part GEMM + pg + bias -> gates -> h,c ----------
// hdst0/hdst1: bf16 dests (stride 1024), hdstf: fp32 dest (stride 512), may be null
__global__ __launch_bounds__(256)
void cell_kernel(const u16* __restrict__ xcat, const u16* __restrict__ Wp,
                 const float* __restrict__ pg, const float* __restrict__ biasp,
                 float* __restrict__ cbuf,
                 u16* __restrict__ hdst0, u16* __restrict__ hdst1,
                 float* __restrict__ hdstf) {
  __shared__ char smem[SMEM_BYTES];
  const int tid = threadIdx.x;
  const int lane = tid & 63, wave = tid >> 6;
  const int m0 = blockIdx.y * 64, n0 = blockIdx.x * 64;

  f32x4 acc[2][2] = {};
  mfma_k512(xcat, 1024, Wp, m0, n0, smem, acc);
  __syncthreads();

  float (*Cs)[68] = (float(*)[68])smem;
  const int wm = (wave >> 1) * 32, wn = (wave & 1) * 32;
  const int col = lane & 15, r4 = (lane >> 4) * 4;
#pragma unroll
  for (int fm = 0; fm < 2; ++fm)
#pragma unroll
    for (int fn = 0; fn < 2; ++fn) {
      int cc = wn + fn * 16 + col;
      float bias = biasp[n0 + cc];
#pragma unroll
      for (int r = 0; r < 4; ++r) {
        int rr = wm + fm * 16 + r4 + r;
        Cs[rr][cc] = acc[fm][fn][r] + pg[(size_t)(m0 + rr) * G4 + n0 + cc] + bias;
      }
    }
  __syncthreads();

  // epilogue: 64 m x 16 j per block
  for (int i = tid; i < 1024; i += 256) {
    int m = i >> 4, j = i & 15;
    float4 gv = *(const float4*)&Cs[m][j * 4];   // i,f,g,o
    float ii = sigm(gv.x), ff = sigm(gv.y), tg = tanhf(gv.z), oo = sigm(gv.w);
    int gm = m0 + m, gj = (n0 >> 2) + j;
    size_t cidx = (size_t)gm * H_DIM + gj;
    float cn = ff * cbuf[cidx] + ii * tg;
    float hn = oo * tanhf(cn);
    cbuf[cidx] = cn;
    u16 hb = f2bf(hn);
    hdst0[(size_t)gm * 1024 + gj] = hb;
    if (hdst1) hdst1[(size_t)gm * 1024 + gj] = hb;
    if (hdstf) hdstf[(size_t)gm * H_DIM + gj] = hn;
  }
}

// ---------------- host ----------------
extern "C" void kernel_launch(void* const* d_in, const int* in_sizes, int n_in,
                              void* d_out, int out_size, void* d_ws, size_t ws_size,
                              hipStream_t stream) {
  (void)in_sizes; (void)n_in; (void)out_size;

  const float* key    = (const float*)d_in[0];
  const float* value  = (const float*)d_in[1];
  const float* mask   = (const float*)d_in[2];
  const int*   labels = (const int*)d_in[3];
  const float* Wq     = (const float*)d_in[4];
  const float* bq     = (const float*)d_in[5];
  const float* Wsc    = (const float*)d_in[6];
  const float* bsc    = (const float*)d_in[7];
  const float* Emb    = (const float*)d_in[8];
  const float* Wih0   = (const float*)d_in[9];
  const float* Whh0   = (const float*)d_in[10];
  const float* bih0   = (const float*)d_in[11];
  const float* bhh0   = (const float*)d_in[12];
  const float* Wih1   = (const float*)d_in[13];
  const float* Whh1   = (const float*)d_in[14];
  const float* bih1   = (const float*)d_in[15];
  const float* bhh1   = (const float*)d_in[16];
  const float* s0     = (const float*)d_in[17];
  const float* s1     = (const float*)d_in[18];
  const float* cs0    = (const float*)d_in[19];
  const float* cs1    = (const float*)d_in[20];
  float* out = (float*)d_out;

  char* ws = (char*)d_ws;
  size_t off = 0;
  auto alloc = [&](size_t bytes) -> void* {
    void* p = ws + off;
    off += (bytes + 255) & ~(size_t)255;
    return p;
  };
  u16*   xcat0  = (u16*)alloc((size_t)B_SZ * 1024 * 2);
  u16*   xcat1  = (u16*)alloc((size_t)B_SZ * 1024 * 2);
  float* h1f    = (float*)alloc((size_t)B_SZ * H_DIM * 4);
  float* c0     = (float*)alloc((size_t)B_SZ * H_DIM * 4);
  float* c1     = (float*)alloc((size_t)B_SZ * H_DIM * 4);
  float* pg0    = (float*)alloc((size_t)B_SZ * G4 * 4);
  float* pg1    = (float*)alloc((size_t)B_SZ * G4 * 4);
  u16*   Wih0p  = (u16*)alloc((size_t)G4 * 512 * 2);
  u16*   Whh0p  = (u16*)alloc((size_t)G4 * 512 * 2);
  u16*   Wih1p  = (u16*)alloc((size_t)G4 * 512 * 2);
  u16*   Whh1p  = (u16*)alloc((size_t)G4 * 512 * 2);
  float* bias0p = (float*)alloc((size_t)G4 * 4);
  float* bias1p = (float*)alloc((size_t)G4 * 4);

  const size_t kv_elems = (size_t)S_LEN * B_SZ * E_DIM;
  const size_t kv_bytes = kv_elems * 2;
  bool bf16kv = (ws_size >= off + 2 * kv_bytes + 512);
  u16* kb = nullptr; u16* vb = nullptr;
  if (bf16kv) {
    kb = (u16*)alloc(kv_bytes);
    vb = (u16*)alloc(kv_bytes);
  }

  init_state<<<(B_SZ * H_DIM) / 256, 256, 0, stream>>>(s0, s1, cs0, cs1,
                                                       xcat0, xcat1, h1f, c0, c1);
  pack_w<<<512, 256, 0, stream>>>(Wih0, Wih0p);
  pack_w<<<512, 256, 0, stream>>>(Whh0, Whh0p);
  pack_w<<<512, 256, 0, stream>>>(Wih1, Wih1p);
  pack_w<<<512, 256, 0, stream>>>(Whh1, Whh1p);
  pack_bias<<<8, 256, 0, stream>>>(bih0, bhh0, bih1, bhh1, bias0p, bias1p);

  if (bf16kv) {
    int n4 = (int)(kv_elems / 4);
    conv_bf16<<<4096, 256, 0, stream>>>(key, kb, n4);
    conv_bf16<<<4096, 256, 0, stream>>>(value, vb, n4);
  }

  dim3 cell_grid(G4 / 64, B_SZ / 64);
  for (int t = 0; t <= T_LEN; ++t) {
    if (bf16kv) {
      fusedA<u16><<<1024, 256, 0, stream>>>(
          kb, vb, mask, labels, Wq, bq, Wsc, bsc, Emb, h1f,
          xcat0, xcat1, Whh0p, Whh1p, pg0, pg1, out, t);
    } else {
      fusedA<float><<<1024, 256, 0, stream>>>(
          key, value, mask, labels, Wq, bq, Wsc, bsc, Emb, h1f,
          xcat0, xcat1, Whh0p, Whh1p, pg0, pg1, out, t);
    }
    if (t < T_LEN) {
      cell_kernel<<<cell_grid, 256, 0, stream>>>(
          xcat0, Wih0p, pg0, bias0p, c0, xcat0 + 512, xcat1, nullptr);
      cell_kernel<<<cell_grid, 256, 0, stream>>>(
          xcat1, Wih1p, pg1, bias1p, c1, xcat1 + 512, nullptr, h1f);
    }
  }
}

// Round 3
// 23091.579 us; speedup vs baseline: 2.2177x; 1.5836x over previous
//
#include <hip/hip_runtime.h>
#include <hip/hip_bf16.h>
#include <cstdint>
#include <cstddef>

#define S_LEN 512
#define B_SZ  512
#define T_LEN 160
#define E_DIM 256
#define H_DIM 512
#define V_DIM 34
#define G4    2048          // 4*H
#define EPS1  1e-12f

typedef unsigned short u16;
typedef __attribute__((ext_vector_type(8))) short bf16x8;
typedef __attribute__((ext_vector_type(4))) float f32x4;

#define SMEM_BYTES 18432    // max(2*64*72*2 staging, 64*68*4 C-tile)

// ---------------- helpers ----------------
__device__ __forceinline__ float wave_reduce_sum(float v) {
#pragma unroll
  for (int m = 32; m >= 1; m >>= 1) v += __shfl_xor(v, m, 64);
  return v;
}
__device__ __forceinline__ float half_reduce_sum(float v) {  // within 32-lane group
#pragma unroll
  for (int m = 16; m >= 1; m >>= 1) v += __shfl_xor(v, m, 64);
  return v;
}
__device__ __forceinline__ float wave_reduce_max(float v) {
#pragma unroll
  for (int m = 32; m >= 1; m >>= 1) v = fmaxf(v, __shfl_xor(v, m, 64));
  return v;
}
__device__ __forceinline__ float bf2f(u16 u) {
  return __uint_as_float((uint32_t)u << 16);
}
__device__ __forceinline__ float4 load4(const float* p) { return *(const float4*)p; }
__device__ __forceinline__ float4 load4(const u16* p) {
  ushort4 u = *(const ushort4*)p;
  float4 r;
  r.x = bf2f(u.x); r.y = bf2f(u.y); r.z = bf2f(u.z); r.w = bf2f(u.w);
  return r;
}
__device__ __forceinline__ float dot8(const u16* p, const float* q) {
  bf16x8 k8 = *(const bf16x8*)p;
  float acc = 0.f;
#pragma unroll
  for (int i = 0; i < 8; ++i) acc += bf2f((u16)k8[i]) * q[i];
  return acc;
}
__device__ __forceinline__ float dot8(const float* p, const float* q) {
  float4 a = *(const float4*)p, b = *(const float4*)(p + 4);
  return a.x*q[0] + a.y*q[1] + a.z*q[2] + a.w*q[3] +
         b.x*q[4] + b.y*q[5] + b.z*q[6] + b.w*q[7];
}
__device__ __forceinline__ u16 f2bf(float f) {
  uint32_t u = __float_as_uint(f);
  uint32_t r = (u + 0x7FFFu + ((u >> 16) & 1u)) >> 16;
  return (u16)r;
}
__device__ __forceinline__ float sigm(float x) { return 1.f / (1.f + __expf(-x)); }

// ---------------- generic MFMA tile accumulate ----------------
// acc += A[m0..m0+63, 0..klen) . W[n0..n0+63, 0..klen)^T
// A row m at A + m*lda ; W row n' at W + n'*ldw (both bf16 u16)
__device__ __forceinline__ void mfma_acc(const u16* A, int lda, const u16* W, int ldw,
                                         int klen, int m0, int n0, char* smem,
                                         f32x4 (&acc)[2][2]) {
  u16 (*As)[72] = (u16(*)[72])smem;
  u16 (*Ws)[72] = (u16(*)[72])(smem + 64 * 72 * 2);
  const int tid = threadIdx.x;
  const int lane = tid & 63, wave = tid >> 6;
  const int wm = (wave >> 1) * 32, wn = (wave & 1) * 32;
  const int row = lane & 15, kq = (lane >> 4) * 8;

  for (int k0 = 0; k0 < klen; k0 += 64) {
    __syncthreads();
#pragma unroll
    for (int i = tid; i < 512; i += 256) {
      int r = i >> 3, c = (i & 7) * 8;
      *(bf16x8*)&As[r][c] = *(const bf16x8*)(A + (size_t)(m0 + r) * lda + k0 + c);
      *(bf16x8*)&Ws[r][c] = *(const bf16x8*)(W + (size_t)(n0 + r) * ldw + k0 + c);
    }
    __syncthreads();
#pragma unroll
    for (int kk = 0; kk < 64; kk += 32) {
      bf16x8 a0 = *(const bf16x8*)&As[wm + row][kk + kq];
      bf16x8 a1 = *(const bf16x8*)&As[wm + 16 + row][kk + kq];
      bf16x8 b0 = *(const bf16x8*)&Ws[wn + row][kk + kq];
      bf16x8 b1 = *(const bf16x8*)&Ws[wn + 16 + row][kk + kq];
      acc[0][0] = __builtin_amdgcn_mfma_f32_16x16x32_bf16(a0, b0, acc[0][0], 0, 0, 0);
      acc[0][1] = __builtin_amdgcn_mfma_f32_16x16x32_bf16(a0, b1, acc[0][1], 0, 0, 0);
      acc[1][0] = __builtin_amdgcn_mfma_f32_16x16x32_bf16(a1, b0, acc[1][0], 0, 0, 0);
      acc[1][1] = __builtin_amdgcn_mfma_f32_16x16x32_bf16(a1, b1, acc[1][1], 0, 0, 0);
    }
  }
}

// ---------------- init ----------------
__global__ __launch_bounds__(256)
void init_state(const float* __restrict__ s0, const float* __restrict__ s1,
                const float* __restrict__ cs0, const float* __restrict__ cs1,
                u16* __restrict__ h0b, u16* __restrict__ h1b,
                float* __restrict__ h1f,
                float* __restrict__ c0, float* __restrict__ c1) {
  int idx = blockIdx.x * blockDim.x + threadIdx.x;  // < B*H
  int j = idx & 511;
  h0b[idx] = f2bf(s0[j]);
  h1b[idx] = f2bf(s1[j]);
  h1f[idx] = s1[j];
  c0[idx] = cs0[j];
  c1[idx] = cs1[j];
}

// ---------------- fp32 -> bf16 (K/V) ----------------
__global__ __launch_bounds__(256)
void conv_bf16(const float* __restrict__ in, u16* __restrict__ outp, int n4) {
  int i = blockIdx.x * blockDim.x + threadIdx.x;
  int stride = gridDim.x * blockDim.x;
  for (; i < n4; i += stride) {
    float4 f = ((const float4*)in)[i];
    ushort4 u;
    u.x = f2bf(f.x); u.y = f2bf(f.y); u.z = f2bf(f.z); u.w = f2bf(f.w);
    ((ushort4*)outp)[i] = u;
  }
}

// ---------------- weight pack: Wp[(j*4+g)][k] = W[g*512+j][k], bf16 -----------
__global__ __launch_bounds__(256)
void pack_w(const float* __restrict__ in, u16* __restrict__ outp) {
  int idx = blockIdx.x * 256 + threadIdx.x;   // 2048*64
  int k = (idx & 63) * 8;
  int np = idx >> 6;
  int j = np >> 2, g = np & 3;
  const float* src = in + ((size_t)(g * 512 + j)) * 512 + k;
  float4 f0 = *(const float4*)src;
  float4 f1 = *(const float4*)(src + 4);
  ushort4 o0, o1;
  o0.x = f2bf(f0.x); o0.y = f2bf(f0.y); o0.z = f2bf(f0.z); o0.w = f2bf(f0.w);
  o1.x = f2bf(f1.x); o1.y = f2bf(f1.y); o1.z = f2bf(f1.z); o1.w = f2bf(f1.w);
  *(ushort4*)(outp + (size_t)np * 512 + k) = o0;
  *(ushort4*)(outp + (size_t)np * 512 + k + 4) = o1;
}

__global__ __launch_bounds__(256)
void pack_wq(const float* __restrict__ in, u16* __restrict__ outp) {
  int idx = blockIdx.x * 256 + threadIdx.x;   // 256*64 = 16384
  int k = (idx & 63) * 8;
  int e = idx >> 6;
  const float* src = in + (size_t)e * 512 + k;
  float4 f0 = *(const float4*)src;
  float4 f1 = *(const float4*)(src + 4);
  ushort4 o0, o1;
  o0.x = f2bf(f0.x); o0.y = f2bf(f0.y); o0.z = f2bf(f0.z); o0.w = f2bf(f0.w);
  o1.x = f2bf(f1.x); o1.y = f2bf(f1.y); o1.z = f2bf(f1.z); o1.w = f2bf(f1.w);
  *(ushort4*)(outp + (size_t)e * 512 + k) = o0;
  *(ushort4*)(outp + (size_t)e * 512 + k + 4) = o1;
}

__global__ __launch_bounds__(256)
void pack_bias(const float* bih0, const float* bhh0,
               const float* bih1, const float* bhh1,
               float* bias0p, float* bias1p) {
  int np = blockIdx.x * 256 + threadIdx.x;  // < 2048
  int j = np >> 2, g = np & 3;
  int n = g * 512 + j;
  bias0p[np] = bih0[n] + bhh0[n];
  bias1p[np] = bih1[n] + bhh1[n];
}

// ---------------- pre-gather all embeddings (bf16) ----------------
__global__ __launch_bounds__(256)
void gather_embs(const float* __restrict__ Emb, const int* __restrict__ labels,
                 u16* __restrict__ embs) {
  int idx = blockIdx.x * 256 + threadIdx.x;   // < T*B*64 quads
  if (idx >= T_LEN * B_SZ * 64) return;
  int q = idx & 63;
  int b = (idx >> 6) & 511;
  int t = idx >> 15;
  int lab = labels[(size_t)b * T_LEN + t];
  float4 f = *(const float4*)(Emb + (size_t)lab * E_DIM + q * 4);
  ushort4 o;
  o.x = f2bf(f.x); o.y = f2bf(f.y); o.z = f2bf(f.z); o.w = f2bf(f.w);
  *(ushort4*)(embs + ((size_t)t * B_SZ + b) * E_DIM + q * 4) = o;
}

// ---------------- kernel A: attend (blocks 0..511) + partial gate GEMMs -------
// pg0 = h0b@Whh0p^T + embs_t@Wih0p[:, :256]^T ; pg1 = h1b@Whh1p^T
template <typename KVT>
__global__ __launch_bounds__(256)
void fusedA(const KVT* __restrict__ key, const KVT* __restrict__ value,
            const float* __restrict__ mask,
            const u16* __restrict__ Wqb, const float* __restrict__ bq,
            const float* __restrict__ Wsc, const float* __restrict__ bsc,
            const u16* __restrict__ embs, const float* __restrict__ h1f,
            const u16* __restrict__ h0b, const u16* __restrict__ h1b,
            const u16* __restrict__ Wih0p, const u16* __restrict__ Whh0p,
            const u16* __restrict__ Whh1p,
            u16* __restrict__ xc0, float* __restrict__ pg0, float* __restrict__ pg1,
            float* __restrict__ out, int t) {
  __shared__ char smem[SMEM_BYTES];
  const int tid = threadIdx.x;
  const int lane = tid & 63;
  const int wave = tid >> 6;

  if (blockIdx.x >= 512) {
    // -------- partial gate GEMM --------
    if (t >= T_LEN) return;
    int gb = blockIdx.x - 512;
    int m0 = ((gb & 255) >> 5) * 64, n0 = (gb & 31) * 64;
    f32x4 acc[2][2] = {};
    float* pg;
    if (gb < 256) {
      mfma_acc(h0b, H_DIM, Whh0p, 512, 512, m0, n0, smem, acc);
      mfma_acc(embs + (size_t)t * B_SZ * E_DIM, E_DIM, Wih0p, 512, 256, m0, n0, smem, acc);
      pg = pg0;
    } else {
      mfma_acc(h1b, H_DIM, Whh1p, 512, 512, m0, n0, smem, acc);
      pg = pg1;
    }
    const int wm = (wave >> 1) * 32, wn = (wave & 1) * 32;
    const int col = lane & 15, r4 = (lane >> 4) * 4;
#pragma unroll
    for (int fm = 0; fm < 2; ++fm)
#pragma unroll
      for (int fn = 0; fn < 2; ++fn) {
        int cc = n0 + wn + fn * 16 + col;
#pragma unroll
        for (int r = 0; r < 4; ++r) {
          int rr = m0 + wm + fm * 16 + r4 + r;
          pg[(size_t)rr * G4 + cc] = acc[fm][fn][r];
        }
      }
    return;
  }

  // -------- attend --------
  float* h1s  = (float*)smem;          // 512
  float* qs   = h1s + 512;             // 256
  float* scb  = qs + 256;              // 512
  float* ctxs = scb + 512;             // 256
  float* ctxp = ctxs + 256;            // 4*256
  float* red  = ctxp + 1024;           // 8
  const int b = blockIdx.x;

#pragma unroll
  for (int j = tid; j < H_DIM; j += 256) h1s[j] = h1f[(size_t)b * H_DIM + j];
  __syncthreads();

  // q = h1 @ Wq^T + bq  (bf16 Wq, wave-cooperative)
  {
    float h8[8];
    *(float4*)&h8[0] = *(const float4*)&h1s[lane * 8];
    *(float4*)&h8[4] = *(const float4*)&h1s[lane * 8 + 4];
    for (int eo = 0; eo < 64; ++eo) {
      int e = (wave << 6) | eo;
      float acc = dot8(Wqb + (size_t)e * 512 + (lane << 3), h8);
      acc = wave_reduce_sum(acc);
      if (lane == 0) qs[e] = acc + bq[e];
    }
  }
  __syncthreads();

  // scores: 2 s-rows per wave-iteration, 16B/lane K loads
  {
    int e0 = (lane & 31) << 3;
    float q8[8];
    *(float4*)&q8[0] = *(const float4*)&qs[e0];
    *(float4*)&q8[4] = *(const float4*)&qs[e0 + 4];
    int s = wave * 2 + (lane >> 5);
    const KVT* kp = key + (size_t)s * (B_SZ * E_DIM) + (size_t)b * E_DIM + e0;
#pragma unroll 4
    for (; s < S_LEN; s += 8) {
      float acc = dot8(kp, q8);
      acc = half_reduce_sum(acc);
      if ((lane & 31) == 0) scb[s] = acc;
      kp += (size_t)8 * B_SZ * E_DIM;
    }
  }
  __syncthreads();

  // masked softmax + renorm
  float v0 = scb[tid], v1 = scb[tid + 256];
  {
    float lm = wave_reduce_max(fmaxf(v0, v1));
    if (lane == 0) red[wave] = lm;
  }
  __syncthreads();
  float smax = fmaxf(fmaxf(red[0], red[1]), fmaxf(red[2], red[3]));
  __syncthreads();
  float m0 = mask[(size_t)b * S_LEN + tid];
  float m1 = mask[(size_t)b * S_LEN + tid + 256];
  float p0 = __expf(v0 - smax), p1 = __expf(v1 - smax);
  float pm0 = p0 * m0, pm1 = p1 * m1;
  {
    float sP = wave_reduce_sum(p0 + p1);
    float sPM = wave_reduce_sum(pm0 + pm1);
    if (lane == 0) { red[wave] = sP; red[4 + wave] = sPM; }
  }
  __syncthreads();
  float P  = red[0] + red[1] + red[2] + red[3];
  float PM = red[4] + red[5] + red[6] + red[7];
  float inv = 1.f / fmaxf(PM, EPS1 * P);
  scb[tid] = pm0 * inv;
  scb[tid + 256] = pm1 * inv;
  __syncthreads();

  // ctx: lane owns e-quad, waves split s 4-way; cross-wave reduce in LDS
  {
    float4 cacc = {0.f, 0.f, 0.f, 0.f};
    const KVT* vp = value + (size_t)wave * (B_SZ * E_DIM) + (size_t)b * E_DIM + (lane << 2);
#pragma unroll 8
    for (int s = wave; s < S_LEN; s += 4) {
      float a = scb[s];
      float4 v4 = load4(vp);
      cacc.x += a * v4.x; cacc.y += a * v4.y; cacc.z += a * v4.z; cacc.w += a * v4.w;
      vp += (size_t)4 * B_SZ * E_DIM;
    }
    *(float4*)&ctxp[wave * 256 + (lane << 2)] = cacc;
  }
  __syncthreads();
  {
    float ctxe = ctxp[tid] + ctxp[256 + tid] + ctxp[512 + tid] + ctxp[768 + tid];
    ctxs[tid] = ctxe;
    if (t < T_LEN) xc0[(size_t)b * E_DIM + tid] = f2bf(ctxe);
  }
  __syncthreads();

  // scoring: out[b, t-1, v] = [h1, ctx] . Wsc[v,:] + bsc[v]
  if (t >= 1) {
    for (int v = wave; v < V_DIM; v += 4) {
      const float4* wr = reinterpret_cast<const float4*>(Wsc + (size_t)v * (H_DIM + E_DIM));
      float4 w0 = wr[lane];
      float4 w1 = wr[lane + 64];
      float4 w2 = wr[lane + 128];
      const float* ha = &h1s[4 * lane];
      const float* hb = &h1s[256 + 4 * lane];
      const float* cx = &ctxs[4 * lane];
      float acc = w0.x * ha[0] + w0.y * ha[1] + w0.z * ha[2] + w0.w * ha[3] +
                  w1.x * hb[0] + w1.y * hb[1] + w1.z * hb[2] + w1.w * hb[3] +
                  w2.x * cx[0] + w2.y * cx[1] + w2.z * cx[2] + w2.w * cx[3];
      acc = wave_reduce_sum(acc);
      if (lane == 0) out[((size_t)b * T_LEN + (t - 1)) * V_DIM + v] = acc + bsc[v];
    }
  }
}

// ---------------- cell kernel: x-part GEMM + pg + bias -> gates -> h,c --------
__global__ __launch_bounds__(256)
void cell_kernel(const u16* __restrict__ A, int lda, const u16* __restrict__ Wp,
                 int klen,
                 const float* __restrict__ pg, const float* __restrict__ biasp,
                 float* __restrict__ cbuf,
                 u16* __restrict__ hb, float* __restrict__ hf) {
  __shared__ char smem[SMEM_BYTES];
  const int tid = threadIdx.x;
  const int lane = tid & 63, wave = tid >> 6;
  const int m0 = blockIdx.y * 64, n0 = blockIdx.x * 64;

  f32x4 acc[2][2] = {};
  mfma_acc(A, lda, Wp, 512, klen, m0, n0, smem, acc);
  __syncthreads();

  float (*Cs)[68] = (float(*)[68])smem;
  const int wm = (wave >> 1) * 32, wn = (wave & 1) * 32;
  const int col = lane & 15, r4 = (lane >> 4) * 4;
#pragma unroll
  for (int fm = 0; fm < 2; ++fm)
#pragma unroll
    for (int fn = 0; fn < 2; ++fn) {
      int cc = wn + fn * 16 + col;
      float bias = biasp[n0 + cc];
#pragma unroll
      for (int r = 0; r < 4; ++r) {
        int rr = wm + fm * 16 + r4 + r;
        Cs[rr][cc] = acc[fm][fn][r] + pg[(size_t)(m0 + rr) * G4 + n0 + cc] + bias;
      }
    }
  __syncthreads();

  // epilogue: 64 m x 16 j per block
  for (int i = tid; i < 1024; i += 256) {
    int m = i >> 4, j = i & 15;
    float4 gv = *(const float4*)&Cs[m][j * 4];   // i,f,g,o
    float ii = sigm(gv.x), ff = sigm(gv.y), tg = tanhf(gv.z), oo = sigm(gv.w);
    int gm = m0 + m, gj = (n0 >> 2) + j;
    size_t cidx = (size_t)gm * H_DIM + gj;
    float cn = ff * cbuf[cidx] + ii * tg;
    float hn = oo * tanhf(cn);
    cbuf[cidx] = cn;
    hb[cidx] = f2bf(hn);
    if (hf) hf[cidx] = hn;
  }
}

// ---------------- host ----------------
extern "C" void kernel_launch(void* const* d_in, const int* in_sizes, int n_in,
                              void* d_out, int out_size, void* d_ws, size_t ws_size,
                              hipStream_t stream) {
  (void)in_sizes; (void)n_in; (void)out_size;

  const float* key    = (const float*)d_in[0];
  const float* value  = (const float*)d_in[1];
  const float* mask   = (const float*)d_in[2];
  const int*   labels = (const int*)d_in[3];
  const float* Wq     = (const float*)d_in[4];
  const float* bq     = (const float*)d_in[5];
  const float* Wsc    = (const float*)d_in[6];
  const float* bsc    = (const float*)d_in[7];
  const float* Emb    = (const float*)d_in[8];
  const float* Wih0   = (const float*)d_in[9];
  const float* Whh0   = (const float*)d_in[10];
  const float* bih0   = (const float*)d_in[11];
  const float* bhh0   = (const float*)d_in[12];
  const float* Wih1   = (const float*)d_in[13];
  const float* Whh1   = (const float*)d_in[14];
  const float* bih1   = (const float*)d_in[15];
  const float* bhh1   = (const float*)d_in[16];
  const float* s0     = (const float*)d_in[17];
  const float* s1     = (const float*)d_in[18];
  const float* cs0    = (const float*)d_in[19];
  const float* cs1    = (const float*)d_in[20];
  float* out = (float*)d_out;

  char* ws = (char*)d_ws;
  size_t off = 0;
  auto alloc = [&](size_t bytes) -> void* {
    void* p = ws + off;
    off += (bytes + 255) & ~(size_t)255;
    return p;
  };
  u16*   h0b    = (u16*)alloc((size_t)B_SZ * H_DIM * 2);
  u16*   h1b    = (u16*)alloc((size_t)B_SZ * H_DIM * 2);
  float* h1f    = (float*)alloc((size_t)B_SZ * H_DIM * 4);
  float* c0     = (float*)alloc((size_t)B_SZ * H_DIM * 4);
  float* c1     = (float*)alloc((size_t)B_SZ * H_DIM * 4);
  u16*   xc0    = (u16*)alloc((size_t)B_SZ * E_DIM * 2);
  float* pg0    = (float*)alloc((size_t)B_SZ * G4 * 4);
  float* pg1    = (float*)alloc((size_t)B_SZ * G4 * 4);
  u16*   Wih0p  = (u16*)alloc((size_t)G4 * 512 * 2);
  u16*   Whh0p  = (u16*)alloc((size_t)G4 * 512 * 2);
  u16*   Wih1p  = (u16*)alloc((size_t)G4 * 512 * 2);
  u16*   Whh1p  = (u16*)alloc((size_t)G4 * 512 * 2);
  u16*   Wqb    = (u16*)alloc((size_t)E_DIM * 512 * 2);
  float* bias0p = (float*)alloc((size_t)G4 * 4);
  float* bias1p = (float*)alloc((size_t)G4 * 4);
  u16*   embs   = (u16*)alloc((size_t)T_LEN * B_SZ * E_DIM * 2);

  const size_t kv_elems = (size_t)S_LEN * B_SZ * E_DIM;
  const size_t kv_bytes = kv_elems * 2;
  bool bf16kv = (ws_size >= off + 2 * kv_bytes + 512);
  u16* kb = nullptr; u16* vb = nullptr;
  if (bf16kv) {
    kb = (u16*)alloc(kv_bytes);
    vb = (u16*)alloc(kv_bytes);
  }

  init_state<<<(B_SZ * H_DIM) / 256, 256, 0, stream>>>(s0, s1, cs0, cs1,
                                                       h0b, h1b, h1f, c0, c1);
  pack_w<<<512, 256, 0, stream>>>(Wih0, Wih0p);
  pack_w<<<512, 256, 0, stream>>>(Whh0, Whh0p);
  pack_w<<<512, 256, 0, stream>>>(Wih1, Wih1p);
  pack_w<<<512, 256, 0, stream>>>(Whh1, Whh1p);
  pack_wq<<<64, 256, 0, stream>>>(Wq, Wqb);
  pack_bias<<<8, 256, 0, stream>>>(bih0, bhh0, bih1, bhh1, bias0p, bias1p);
  gather_embs<<<(T_LEN * B_SZ * 64 + 255) / 256, 256, 0, stream>>>(Emb, labels, embs);

  if (bf16kv) {
    int n4 = (int)(kv_elems / 4);
    conv_bf16<<<4096, 256, 0, stream>>>(key, kb, n4);
    conv_bf16<<<4096, 256, 0, stream>>>(value, vb, n4);
  }

  dim3 cell_grid(G4 / 64, B_SZ / 64);
  for (int t = 0; t <= T_LEN; ++t) {
    if (bf16kv) {
      fusedA<u16><<<1024, 256, 0, stream>>>(
          kb, vb, mask, Wqb, bq, Wsc, bsc, embs, h1f, h0b, h1b,
          Wih0p, Whh0p, Whh1p, xc0, pg0, pg1, out, t);
    } else {
      fusedA<float><<<1024, 256, 0, stream>>>(
          key, value, mask, Wqb, bq, Wsc, bsc, embs, h1f, h0b, h1b,
          Wih0p, Whh0p, Whh1p, xc0, pg0, pg1, out, t);
    }
    if (t < T_LEN) {
      // cell0: ctx part only (K=256, Wih0 cols 256..511) + pg0
      cell_kernel<<<cell_grid, 256, 0, stream>>>(
          xc0, E_DIM, Wih0p + 256, 256, pg0, bias0p, c0, h0b, nullptr);
      // cell1: x = h0 (K=512) + pg1
      cell_kernel<<<cell_grid, 256, 0, stream>>>(
          h0b, H_DIM, Wih1p, 512, pg1, bias1p, c1, h1b, h1f);
    }
  }
}

// Round 4
// 17791.121 us; speedup vs baseline: 2.8785x; 1.2979x over previous
//
#include <hip/hip_runtime.h>
#include <hip/hip_bf16.h>
#include <cstdint>
#include <cstddef>

#define S_LEN 512
#define B_SZ  512
#define T_LEN 160
#define E_DIM 256
#define H_DIM 512
#define V_DIM 34
#define G4    2048          // 4*H
#define XROW  768           // [h1 (512) | ctx (256)] history row
#define EPS1  1e-12f

typedef unsigned short u16;
typedef __attribute__((ext_vector_type(8))) short bf16x8;
typedef __attribute__((ext_vector_type(4))) float f32x4;

#define SMEM_BYTES 18432    // 2*64*72*2 staging

// ---------------- helpers ----------------
__device__ __forceinline__ float wave_reduce_sum(float v) {
#pragma unroll
  for (int m = 32; m >= 1; m >>= 1) v += __shfl_xor(v, m, 64);
  return v;
}
__device__ __forceinline__ float half_reduce_sum(float v) {  // within 32-lane group
#pragma unroll
  for (int m = 16; m >= 1; m >>= 1) v += __shfl_xor(v, m, 64);
  return v;
}
__device__ __forceinline__ float wave_reduce_max(float v) {
#pragma unroll
  for (int m = 32; m >= 1; m >>= 1) v = fmaxf(v, __shfl_xor(v, m, 64));
  return v;
}
__device__ __forceinline__ float bf2f(u16 u) {
  return __uint_as_float((uint32_t)u << 16);
}
__device__ __forceinline__ float4 load4(const float* p) { return *(const float4*)p; }
__device__ __forceinline__ float4 load4(const u16* p) {
  ushort4 u = *(const ushort4*)p;
  float4 r;
  r.x = bf2f(u.x); r.y = bf2f(u.y); r.z = bf2f(u.z); r.w = bf2f(u.w);
  return r;
}
__device__ __forceinline__ float dot8(const u16* p, const float* q) {
  bf16x8 k8 = *(const bf16x8*)p;
  float acc = 0.f;
#pragma unroll
  for (int i = 0; i < 8; ++i) acc += bf2f((u16)k8[i]) * q[i];
  return acc;
}
__device__ __forceinline__ float dot8(const float* p, const float* q) {
  float4 a = *(const float4*)p, b = *(const float4*)(p + 4);
  return a.x*q[0] + a.y*q[1] + a.z*q[2] + a.w*q[3] +
         b.x*q[4] + b.y*q[5] + b.z*q[6] + b.w*q[7];
}
__device__ __forceinline__ u16 f2bf(float f) {
  uint32_t u = __float_as_uint(f);
  uint32_t r = (u + 0x7FFFu + ((u >> 16) & 1u)) >> 16;
  return (u16)r;
}
__device__ __forceinline__ float sigm(float x) { return 1.f / (1.f + __expf(-x)); }

// ---------------- generic MFMA tile accumulate ----------------
// acc += A[m0..m0+63, 0..klen) . W[n0..n0+63, 0..klen)^T
__device__ __forceinline__ void mfma_acc(const u16* A, int lda, const u16* W, int ldw,
                                         int klen, int m0, int n0, char* smem,
                                         f32x4 (&acc)[2][2]) {
  u16 (*As)[72] = (u16(*)[72])smem;
  u16 (*Ws)[72] = (u16(*)[72])(smem + 64 * 72 * 2);
  const int tid = threadIdx.x;
  const int lane = tid & 63, wave = tid >> 6;
  const int wm = (wave >> 1) * 32, wn = (wave & 1) * 32;
  const int row = lane & 15, kq = (lane >> 4) * 8;

  for (int k0 = 0; k0 < klen; k0 += 64) {
    __syncthreads();
#pragma unroll
    for (int i = tid; i < 512; i += 256) {
      int r = i >> 3, c = (i & 7) * 8;
      *(bf16x8*)&As[r][c] = *(const bf16x8*)(A + (size_t)(m0 + r) * lda + k0 + c);
      *(bf16x8*)&Ws[r][c] = *(const bf16x8*)(W + (size_t)(n0 + r) * ldw + k0 + c);
    }
    __syncthreads();
#pragma unroll
    for (int kk = 0; kk < 64; kk += 32) {
      bf16x8 a0 = *(const bf16x8*)&As[wm + row][kk + kq];
      bf16x8 a1 = *(const bf16x8*)&As[wm + 16 + row][kk + kq];
      bf16x8 b0 = *(const bf16x8*)&Ws[wn + row][kk + kq];
      bf16x8 b1 = *(const bf16x8*)&Ws[wn + 16 + row][kk + kq];
      acc[0][0] = __builtin_amdgcn_mfma_f32_16x16x32_bf16(a0, b0, acc[0][0], 0, 0, 0);
      acc[0][1] = __builtin_amdgcn_mfma_f32_16x16x32_bf16(a0, b1, acc[0][1], 0, 0, 0);
      acc[1][0] = __builtin_amdgcn_mfma_f32_16x16x32_bf16(a1, b0, acc[1][0], 0, 0, 0);
      acc[1][1] = __builtin_amdgcn_mfma_f32_16x16x32_bf16(a1, b1, acc[1][1], 0, 0, 0);
    }
  }
}

// ---------------- init ----------------
__global__ __launch_bounds__(256)
void init_state(const float* __restrict__ s0, const float* __restrict__ s1,
                const float* __restrict__ cs0, const float* __restrict__ cs1,
                u16* __restrict__ h0b, u16* __restrict__ h1b,
                float* __restrict__ c0, float* __restrict__ c1) {
  int idx = blockIdx.x * blockDim.x + threadIdx.x;  // < B*H
  int j = idx & 511;
  h0b[idx] = f2bf(s0[j]);
  h1b[idx] = f2bf(s1[j]);
  c0[idx] = cs0[j];
  c1[idx] = cs1[j];
}

// ---------------- fp32 -> bf16 (K/V) ----------------
__global__ __launch_bounds__(256)
void conv_bf16(const float* __restrict__ in, u16* __restrict__ outp, int n4) {
  int i = blockIdx.x * blockDim.x + threadIdx.x;
  int stride = gridDim.x * blockDim.x;
  for (; i < n4; i += stride) {
    float4 f = ((const float4*)in)[i];
    ushort4 u;
    u.x = f2bf(f.x); u.y = f2bf(f.y); u.z = f2bf(f.z); u.w = f2bf(f.w);
    ((ushort4*)outp)[i] = u;
  }
}

// ---------------- weight packs ----------------
__global__ __launch_bounds__(256)
void pack_w(const float* __restrict__ in, u16* __restrict__ outp) {
  int idx = blockIdx.x * 256 + threadIdx.x;   // 2048*64
  int k = (idx & 63) * 8;
  int np = idx >> 6;
  int j = np >> 2, g = np & 3;
  const float* src = in + ((size_t)(g * 512 + j)) * 512 + k;
  float4 f0 = *(const float4*)src;
  float4 f1 = *(const float4*)(src + 4);
  ushort4 o0, o1;
  o0.x = f2bf(f0.x); o0.y = f2bf(f0.y); o0.z = f2bf(f0.z); o0.w = f2bf(f0.w);
  o1.x = f2bf(f1.x); o1.y = f2bf(f1.y); o1.z = f2bf(f1.z); o1.w = f2bf(f1.w);
  *(ushort4*)(outp + (size_t)np * 512 + k) = o0;
  *(ushort4*)(outp + (size_t)np * 512 + k + 4) = o1;
}

__global__ __launch_bounds__(256)
void pack_wq(const float* __restrict__ in, u16* __restrict__ outp) {
  int idx = blockIdx.x * 256 + threadIdx.x;   // 256*64
  int k = (idx & 63) * 8;
  int e = idx >> 6;
  const float* src = in + (size_t)e * 512 + k;
  float4 f0 = *(const float4*)src;
  float4 f1 = *(const float4*)(src + 4);
  ushort4 o0, o1;
  o0.x = f2bf(f0.x); o0.y = f2bf(f0.y); o0.z = f2bf(f0.z); o0.w = f2bf(f0.w);
  o1.x = f2bf(f1.x); o1.y = f2bf(f1.y); o1.z = f2bf(f1.z); o1.w = f2bf(f1.w);
  *(ushort4*)(outp + (size_t)e * 512 + k) = o0;
  *(ushort4*)(outp + (size_t)e * 512 + k + 4) = o1;
}

// Wscb: 64 rows x 768 cols, rows >= V_DIM zeroed
__global__ __launch_bounds__(256)
void pack_wsc(const float* __restrict__ in, u16* __restrict__ outp) {
  int idx = blockIdx.x * 256 + threadIdx.x;   // 64*96 = 6144
  if (idx >= 64 * 96) return;
  int kq = (idx % 96) * 8;
  int v = idx / 96;
  ushort4 o0 = {0, 0, 0, 0}, o1 = {0, 0, 0, 0};
  if (v < V_DIM) {
    const float* src = in + (size_t)v * XROW + kq;
    float4 f0 = *(const float4*)src;
    float4 f1 = *(const float4*)(src + 4);
    o0.x = f2bf(f0.x); o0.y = f2bf(f0.y); o0.z = f2bf(f0.z); o0.w = f2bf(f0.w);
    o1.x = f2bf(f1.x); o1.y = f2bf(f1.y); o1.z = f2bf(f1.z); o1.w = f2bf(f1.w);
  }
  *(ushort4*)(outp + (size_t)v * XROW + kq) = o0;
  *(ushort4*)(outp + (size_t)v * XROW + kq + 4) = o1;
}

__global__ __launch_bounds__(256)
void pack_bias(const float* bih0, const float* bhh0,
               const float* bih1, const float* bhh1,
               float* bias0p, float* bias1p) {
  int np = blockIdx.x * 256 + threadIdx.x;  // < 2048
  int j = np >> 2, g = np & 3;
  int n = g * 512 + j;
  bias0p[np] = bih0[n] + bhh0[n];
  bias1p[np] = bih1[n] + bhh1[n];
}

// ---------------- pre-gather all embeddings (bf16) ----------------
__global__ __launch_bounds__(256)
void gather_embs(const float* __restrict__ Emb, const int* __restrict__ labels,
                 u16* __restrict__ embs) {
  int idx = blockIdx.x * 256 + threadIdx.x;   // < T*B*64 quads
  if (idx >= T_LEN * B_SZ * 64) return;
  int q = idx & 63;
  int b = (idx >> 6) & 511;
  int t = idx >> 15;
  int lab = labels[(size_t)b * T_LEN + t];
  float4 f = *(const float4*)(Emb + (size_t)lab * E_DIM + q * 4);
  ushort4 o;
  o.x = f2bf(f.x); o.y = f2bf(f.y); o.z = f2bf(f.z); o.w = f2bf(f.w);
  *(ushort4*)(embs + ((size_t)t * B_SZ + b) * E_DIM + q * 4) = o;
}

// ---------------- q GEMM: qbuf(B,256) = h1b(B,512) @ Wqb^T + bq ----------------
__global__ __launch_bounds__(256)
void qgemm(const u16* __restrict__ h1b, const u16* __restrict__ Wqb,
           const float* __restrict__ bq, float* __restrict__ qbuf) {
  __shared__ char smem[SMEM_BYTES];
  const int lane = threadIdx.x & 63, wave = threadIdx.x >> 6;
  const int m0 = blockIdx.y * 64, n0 = blockIdx.x * 64;
  f32x4 acc[2][2] = {};
  mfma_acc(h1b, H_DIM, Wqb, 512, 512, m0, n0, smem, acc);
  const int wm = (wave >> 1) * 32, wn = (wave & 1) * 32;
  const int col = lane & 15, r4 = (lane >> 4) * 4;
#pragma unroll
  for (int fm = 0; fm < 2; ++fm)
#pragma unroll
    for (int fn = 0; fn < 2; ++fn) {
      int cc = n0 + wn + fn * 16 + col;
      float bias = bq[cc];
#pragma unroll
      for (int r = 0; r < 4; ++r) {
        int rr = m0 + wm + fm * 16 + r4 + r;
        qbuf[(size_t)rr * E_DIM + cc] = acc[fm][fn][r] + bias;
      }
    }
}

// ---------------- kernel A: attend (blocks 0..511) + partial gate GEMMs -------
template <typename KVT, bool DEFER>
__global__ __launch_bounds__(256)
void fusedA(const KVT* __restrict__ key, const KVT* __restrict__ value,
            const float* __restrict__ mask, const float* __restrict__ qbuf,
            const float* __restrict__ Wsc, const float* __restrict__ bsc,
            const u16* __restrict__ embs,
            const u16* __restrict__ h0b, const u16* __restrict__ h1b,
            const u16* __restrict__ Wih0p, const u16* __restrict__ Whh0p,
            const u16* __restrict__ Whh1p,
            u16* __restrict__ xc0, u16* __restrict__ xhist,
            float* __restrict__ pg0, float* __restrict__ pg1,
            float* __restrict__ out, int t) {
  __shared__ char smem[SMEM_BYTES];
  const int tid = threadIdx.x;
  const int lane = tid & 63;
  const int wave = tid >> 6;

  if (blockIdx.x >= 512) {
    // -------- partial gate GEMM --------
    if (t >= T_LEN) return;
    int gb = blockIdx.x - 512;
    int m0 = ((gb & 255) >> 5) * 64, n0 = (gb & 31) * 64;
    f32x4 acc[2][2] = {};
    float* pg;
    if (gb < 256) {
      mfma_acc(h0b, H_DIM, Whh0p, 512, 512, m0, n0, smem, acc);
      mfma_acc(embs + (size_t)t * B_SZ * E_DIM, E_DIM, Wih0p, 512, 256, m0, n0, smem, acc);
      pg = pg0;
    } else {
      mfma_acc(h1b, H_DIM, Whh1p, 512, 512, m0, n0, smem, acc);
      pg = pg1;
    }
    const int wm = (wave >> 1) * 32, wn = (wave & 1) * 32;
    const int col = lane & 15, r4 = (lane >> 4) * 4;
#pragma unroll
    for (int fm = 0; fm < 2; ++fm)
#pragma unroll
      for (int fn = 0; fn < 2; ++fn) {
        int cc = n0 + wn + fn * 16 + col;
#pragma unroll
        for (int r = 0; r < 4; ++r) {
          int rr = m0 + wm + fm * 16 + r4 + r;
          pg[(size_t)rr * G4 + cc] = acc[fm][fn][r];
        }
      }
    return;
  }

  // -------- attend --------
  float* qs   = (float*)smem;          // 256
  float* scb  = qs + 256;              // 512
  float* ctxs = scb + 512;             // 256
  float* ctxp = ctxs + 256;            // 4*256
  float* red  = ctxp + 1024;           // 8
  float* h1s  = red + 8;               // 512 (fallback scoring only)
  const int b = blockIdx.x;

  qs[tid] = qbuf[(size_t)b * E_DIM + tid];
  if (!DEFER) {
#pragma unroll
    for (int j = tid; j < H_DIM; j += 256) h1s[j] = bf2f(h1b[(size_t)b * H_DIM + j]);
  }
  __syncthreads();

  // scores: 2 s-rows per wave-iteration, 16B/lane K loads
  {
    int e0 = (lane & 31) << 3;
    float q8[8];
    *(float4*)&q8[0] = *(const float4*)&qs[e0];
    *(float4*)&q8[4] = *(const float4*)&qs[e0 + 4];
    int s = wave * 2 + (lane >> 5);
    const KVT* kp = key + (size_t)s * (B_SZ * E_DIM) + (size_t)b * E_DIM + e0;
#pragma unroll 4
    for (; s < S_LEN; s += 8) {
      float acc = dot8(kp, q8);
      acc = half_reduce_sum(acc);
      if ((lane & 31) == 0) scb[s] = acc;
      kp += (size_t)8 * B_SZ * E_DIM;
    }
  }
  __syncthreads();

  // masked softmax + renorm
  float v0 = scb[tid], v1 = scb[tid + 256];
  {
    float lm = wave_reduce_max(fmaxf(v0, v1));
    if (lane == 0) red[wave] = lm;
  }
  __syncthreads();
  float smax = fmaxf(fmaxf(red[0], red[1]), fmaxf(red[2], red[3]));
  __syncthreads();
  float m0 = mask[(size_t)b * S_LEN + tid];
  float m1 = mask[(size_t)b * S_LEN + tid + 256];
  float p0 = __expf(v0 - smax), p1 = __expf(v1 - smax);
  float pm0 = p0 * m0, pm1 = p1 * m1;
  {
    float sP = wave_reduce_sum(p0 + p1);
    float sPM = wave_reduce_sum(pm0 + pm1);
    if (lane == 0) { red[wave] = sP; red[4 + wave] = sPM; }
  }
  __syncthreads();
  float P  = red[0] + red[1] + red[2] + red[3];
  float PM = red[4] + red[5] + red[6] + red[7];
  float inv = 1.f / fmaxf(PM, EPS1 * P);
  scb[tid] = pm0 * inv;
  scb[tid + 256] = pm1 * inv;
  __syncthreads();

  // ctx: lane owns e-quad, waves split s 4-way; cross-wave reduce in LDS
  {
    float4 cacc = {0.f, 0.f, 0.f, 0.f};
    const KVT* vp = value + (size_t)wave * (B_SZ * E_DIM) + (size_t)b * E_DIM + (lane << 2);
#pragma unroll 8
    for (int s = wave; s < S_LEN; s += 4) {
      float a = scb[s];
      float4 v4 = load4(vp);
      cacc.x += a * v4.x; cacc.y += a * v4.y; cacc.z += a * v4.z; cacc.w += a * v4.w;
      vp += (size_t)4 * B_SZ * E_DIM;
    }
    *(float4*)&ctxp[wave * 256 + (lane << 2)] = cacc;
  }
  __syncthreads();
  {
    float ctxe = ctxp[tid] + ctxp[256 + tid] + ctxp[512 + tid] + ctxp[768 + tid];
    ctxs[tid] = ctxe;
    u16 cb = f2bf(ctxe);
    if (t < T_LEN) xc0[(size_t)b * E_DIM + tid] = cb;
    if (DEFER && t >= 1) xhist[((size_t)t * B_SZ + b) * XROW + H_DIM + tid] = cb;
  }

  if (!DEFER) {
    __syncthreads();
    if (t >= 1) {
      for (int v = wave; v < V_DIM; v += 4) {
        const float4* wr = reinterpret_cast<const float4*>(Wsc + (size_t)v * XROW);
        float4 w0 = wr[lane];
        float4 w1 = wr[lane + 64];
        float4 w2 = wr[lane + 128];
        const float* ha = &h1s[4 * lane];
        const float* hb = &h1s[256 + 4 * lane];
        const float* cx = &ctxs[4 * lane];
        float acc = w0.x * ha[0] + w0.y * ha[1] + w0.z * ha[2] + w0.w * ha[3] +
                    w1.x * hb[0] + w1.y * hb[1] + w1.z * hb[2] + w1.w * hb[3] +
                    w2.x * cx[0] + w2.y * cx[1] + w2.z * cx[2] + w2.w * cx[3];
        acc = wave_reduce_sum(acc);
        if (lane == 0) out[((size_t)b * T_LEN + (t - 1)) * V_DIM + v] = acc + bsc[v];
      }
    }
  }
}

// ---------------- cell kernel: x-part GEMM + pg + bias -> gates -> h,c --------
__global__ __launch_bounds__(256)
void cell_kernel(const u16* __restrict__ A, int lda, const u16* __restrict__ Wp,
                 int klen,
                 const float* __restrict__ pg, const float* __restrict__ biasp,
                 float* __restrict__ cbuf,
                 u16* __restrict__ hb, u16* __restrict__ xh) {
  __shared__ char smem[SMEM_BYTES];
  const int tid = threadIdx.x;
  const int lane = tid & 63, wave = tid >> 6;
  const int m0 = blockIdx.y * 64, n0 = blockIdx.x * 64;

  f32x4 acc[2][2] = {};
  mfma_acc(A, lda, Wp, 512, klen, m0, n0, smem, acc);
  __syncthreads();

  float (*Cs)[68] = (float(*)[68])smem;
  const int wm = (wave >> 1) * 32, wn = (wave & 1) * 32;
  const int col = lane & 15, r4 = (lane >> 4) * 4;
#pragma unroll
  for (int fm = 0; fm < 2; ++fm)
#pragma unroll
    for (int fn = 0; fn < 2; ++fn) {
      int cc = wn + fn * 16 + col;
      float bias = biasp[n0 + cc];
#pragma unroll
      for (int r = 0; r < 4; ++r) {
        int rr = wm + fm * 16 + r4 + r;
        Cs[rr][cc] = acc[fm][fn][r] + pg[(size_t)(m0 + rr) * G4 + n0 + cc] + bias;
      }
    }
  __syncthreads();

  // epilogue: 64 m x 16 j per block
  for (int i = tid; i < 1024; i += 256) {
    int m = i >> 4, j = i & 15;
    float4 gv = *(const float4*)&Cs[m][j * 4];   // i,f,g,o
    float ii = sigm(gv.x), ff = sigm(gv.y), tg = tanhf(gv.z), oo = sigm(gv.w);
    int gm = m0 + m, gj = (n0 >> 2) + j;
    size_t cidx = (size_t)gm * H_DIM + gj;
    float cn = ff * cbuf[cidx] + ii * tg;
    float hn = oo * tanhf(cn);
    cbuf[cidx] = cn;
    u16 hv = f2bf(hn);
    hb[cidx] = hv;
    if (xh) xh[(size_t)gm * XROW + gj] = hv;
  }
}

// ---------------- deferred scoring: out = xhist @ Wscb^T + bsc ----------------
__global__ __launch_bounds__(256)
void score_kernel(const u16* __restrict__ xhist, const u16* __restrict__ Wscb,
                  const float* __restrict__ bsc, float* __restrict__ out) {
  __shared__ char smem[SMEM_BYTES];
  const int tau = blockIdx.x + 1;        // 1..160
  const int m0 = blockIdx.y * 64;        // b base
  const int lane = threadIdx.x & 63, wave = threadIdx.x >> 6;
  f32x4 acc[2][2] = {};
  mfma_acc(xhist + (size_t)tau * B_SZ * XROW, XROW, Wscb, XROW, XROW, m0, 0, smem, acc);
  const int wm = (wave >> 1) * 32, wn = (wave & 1) * 32;
  const int col = lane & 15, r4 = (lane >> 4) * 4;
#pragma unroll
  for (int fm = 0; fm < 2; ++fm)
#pragma unroll
    for (int fn = 0; fn < 2; ++fn) {
      int cc = wn + fn * 16 + col;
      if (cc >= V_DIM) continue;
      float bias = bsc[cc];
#pragma unroll
      for (int r = 0; r < 4; ++r) {
        int b = m0 + wm + fm * 16 + r4 + r;
        out[((size_t)b * T_LEN + (tau - 1)) * V_DIM + cc] = acc[fm][fn][r] + bias;
      }
    }
}

// ---------------- host ----------------
extern "C" void kernel_launch(void* const* d_in, const int* in_sizes, int n_in,
                              void* d_out, int out_size, void* d_ws, size_t ws_size,
                              hipStream_t stream) {
  (void)in_sizes; (void)n_in; (void)out_size;

  const float* key    = (const float*)d_in[0];
  const float* value  = (const float*)d_in[1];
  const float* mask   = (const float*)d_in[2];
  const int*   labels = (const int*)d_in[3];
  const float* Wq     = (const float*)d_in[4];
  const float* bq     = (const float*)d_in[5];
  const float* Wsc    = (const float*)d_in[6];
  const float* bsc    = (const float*)d_in[7];
  const float* Emb    = (const float*)d_in[8];
  const float* Wih0   = (const float*)d_in[9];
  const float* Whh0   = (const float*)d_in[10];
  const float* bih0   = (const float*)d_in[11];
  const float* bhh0   = (const float*)d_in[12];
  const float* Wih1   = (const float*)d_in[13];
  const float* Whh1   = (const float*)d_in[14];
  const float* bih1   = (const float*)d_in[15];
  const float* bhh1   = (const float*)d_in[16];
  const float* s0     = (const float*)d_in[17];
  const float* s1     = (const float*)d_in[18];
  const float* cs0    = (const float*)d_in[19];
  const float* cs1    = (const float*)d_in[20];
  float* out = (float*)d_out;

  char* ws = (char*)d_ws;
  size_t off = 0;
  auto alloc = [&](size_t bytes) -> void* {
    void* p = ws + off;
    off += (bytes + 255) & ~(size_t)255;
    return p;
  };
  u16*   h0b    = (u16*)alloc((size_t)B_SZ * H_DIM * 2);
  u16*   h1b    = (u16*)alloc((size_t)B_SZ * H_DIM * 2);
  float* c0     = (float*)alloc((size_t)B_SZ * H_DIM * 4);
  float* c1     = (float*)alloc((size_t)B_SZ * H_DIM * 4);
  u16*   xc0    = (u16*)alloc((size_t)B_SZ * E_DIM * 2);
  float* qbuf   = (float*)alloc((size_t)B_SZ * E_DIM * 4);
  float* pg0    = (float*)alloc((size_t)B_SZ * G4 * 4);
  float* pg1    = (float*)alloc((size_t)B_SZ * G4 * 4);
  u16*   Wih0p  = (u16*)alloc((size_t)G4 * 512 * 2);
  u16*   Whh0p  = (u16*)alloc((size_t)G4 * 512 * 2);
  u16*   Wih1p  = (u16*)alloc((size_t)G4 * 512 * 2);
  u16*   Whh1p  = (u16*)alloc((size_t)G4 * 512 * 2);
  u16*   Wqb    = (u16*)alloc((size_t)E_DIM * 512 * 2);
  u16*   Wscb   = (u16*)alloc((size_t)64 * XROW * 2);
  float* bias0p = (float*)alloc((size_t)G4 * 4);
  float* bias1p = (float*)alloc((size_t)G4 * 4);
  u16*   embs   = (u16*)alloc((size_t)T_LEN * B_SZ * E_DIM * 2);

  const size_t kv_elems = (size_t)S_LEN * B_SZ * E_DIM;
  const size_t kv_bytes = kv_elems * 2;
  bool bf16kv = (ws_size >= off + 2 * kv_bytes + 1024);
  u16* kb = nullptr; u16* vb = nullptr;
  if (bf16kv) {
    kb = (u16*)alloc(kv_bytes);
    vb = (u16*)alloc(kv_bytes);
  }
  const size_t xh_bytes = (size_t)(T_LEN + 1) * B_SZ * XROW * 2;
  bool defer = (ws_size >= off + xh_bytes + 1024);
  u16* xhist = nullptr;
  if (defer) xhist = (u16*)alloc(xh_bytes);

  init_state<<<(B_SZ * H_DIM) / 256, 256, 0, stream>>>(s0, s1, cs0, cs1, h0b, h1b, c0, c1);
  pack_w<<<512, 256, 0, stream>>>(Wih0, Wih0p);
  pack_w<<<512, 256, 0, stream>>>(Whh0, Whh0p);
  pack_w<<<512, 256, 0, stream>>>(Wih1, Wih1p);
  pack_w<<<512, 256, 0, stream>>>(Whh1, Whh1p);
  pack_wq<<<64, 256, 0, stream>>>(Wq, Wqb);
  if (defer) pack_wsc<<<24, 256, 0, stream>>>(Wsc, Wscb);
  pack_bias<<<8, 256, 0, stream>>>(bih0, bhh0, bih1, bhh1, bias0p, bias1p);
  gather_embs<<<(T_LEN * B_SZ * 64 + 255) / 256, 256, 0, stream>>>(Emb, labels, embs);

  if (bf16kv) {
    int n4 = (int)(kv_elems / 4);
    conv_bf16<<<4096, 256, 0, stream>>>(key, kb, n4);
    conv_bf16<<<4096, 256, 0, stream>>>(value, vb, n4);
  }

  dim3 qgrid(E_DIM / 64, B_SZ / 64);
  qgemm<<<qgrid, 256, 0, stream>>>(h1b, Wqb, bq, qbuf);  // q for t=0

  dim3 cell_grid(G4 / 64, B_SZ / 64);
  for (int t = 0; t <= T_LEN; ++t) {
    if (bf16kv) {
      if (defer)
        fusedA<u16, true><<<1024, 256, 0, stream>>>(
            kb, vb, mask, qbuf, Wsc, bsc, embs, h0b, h1b,
            Wih0p, Whh0p, Whh1p, xc0, xhist, pg0, pg1, out, t);
      else
        fusedA<u16, false><<<1024, 256, 0, stream>>>(
            kb, vb, mask, qbuf, Wsc, bsc, embs, h0b, h1b,
            Wih0p, Whh0p, Whh1p, xc0, xhist, pg0, pg1, out, t);
    } else {
      if (defer)
        fusedA<float, true><<<1024, 256, 0, stream>>>(
            key, value, mask, qbuf, Wsc, bsc, embs, h0b, h1b,
            Wih0p, Whh0p, Whh1p, xc0, xhist, pg0, pg1, out, t);
      else
        fusedA<float, false><<<1024, 256, 0, stream>>>(
            key, value, mask, qbuf, Wsc, bsc, embs, h0b, h1b,
            Wih0p, Whh0p, Whh1p, xc0, xhist, pg0, pg1, out, t);
    }
    if (t < T_LEN) {
      // cell0: ctx part only (K=256, Wih0 cols 256..511) + pg0
      cell_kernel<<<cell_grid, 256, 0, stream>>>(
          xc0, E_DIM, Wih0p + 256, 256, pg0, bias0p, c0, h0b, nullptr);
      // cell1: x = h0 (K=512) + pg1 ; also store h into xhist slot t+1
      cell_kernel<<<cell_grid, 256, 0, stream>>>(
          h0b, H_DIM, Wih1p, 512, pg1, bias1p, c1, h1b,
          defer ? xhist + (size_t)(t + 1) * B_SZ * XROW : nullptr);
      // q for t+1
      qgemm<<<qgrid, 256, 0, stream>>>(h1b, Wqb, bq, qbuf);
    }
  }

  if (defer) {
    dim3 sgrid(T_LEN, B_SZ / 64);
    score_kernel<<<sgrid, 256, 0, stream>>>(xhist, Wscb, bsc, out);
  }
}